// Round 1
// baseline (90.481 us; speedup 1.0000x reference)
//
#include <hip/hip_runtime.h>
#include <math.h>

#define NVERT 289
#define NFACE 512

// One block per 16x16 pixel tile; 64 blocks x 256 threads.
// Each block: verts -> LDS, face setup -> LDS, bbox binning, per-pixel
// top-8 soft rasterization + shading.
__global__ __launch_bounds__(256) void nvp_kernel(
    const float* __restrict__ xy_off,
    const float* __restrict__ z_grid,
    const float* __restrict__ texd,
    const float* __restrict__ R_in,
    const float* __restrict__ T_in,
    const float* __restrict__ R_out,
    const float* __restrict__ T_out,
    float* __restrict__ out)
{
    __shared__ __align__(16) float s_f[NFACE * 28];
    __shared__ float s_vx[NVERT], s_vy[NVERT], s_vz[NVERT];
    __shared__ unsigned char s_flag[NFACE];
    __shared__ int s_list[NFACE];
    __shared__ int s_nf;

    const int tid = threadIdx.x;
    const int tileX = blockIdx.x & 7;
    const int tileY = blockIdx.x >> 3;

    const float SC = 0.57735026918962576f;       // tan(30 deg), fp32
    const float SI = 1.0f / 0.57735026918962576f; // 1/SCALE, constant-folded

    // ---------------- Phase 0: screen-space vertices ----------------
    for (int v = tid; v < NVERT; v += 256) {
        int ix = v % 17, iy = v / 17;
        float gx = -1.0f + 0.125f * (float)ix;
        float gy = -1.0f + 0.125f * (float)iy;
        float sx = (gx + xy_off[2 * v]) * SC;
        float sy = (gy + xy_off[2 * v + 1]) * SC;
        float z = z_grid[v];
        float X = sx * z, Y = sy * z, Z = z;
        float p0 = X - T_in[0], p1 = Y - T_in[1], p2 = Z - T_in[2];
        float wxx = R_in[0] * p0 + R_in[1] * p1 + R_in[2] * p2;
        float wyy = R_in[3] * p0 + R_in[4] * p1 + R_in[5] * p2;
        float wzz = R_in[6] * p0 + R_in[7] * p1 + R_in[8] * p2;
        float vx = wxx * R_out[0] + wyy * R_out[3] + wzz * R_out[6] + T_out[0];
        float vy = wxx * R_out[1] + wyy * R_out[4] + wzz * R_out[7] + T_out[1];
        float vz = wxx * R_out[2] + wyy * R_out[5] + wzz * R_out[8] + T_out[2];
        float zden = (vz >= 0.0f) ? fmaxf(vz, 0.01f) : fminf(vz, -0.01f);
        s_vx[v] = SI * vx / zden;
        s_vy[v] = SI * vy / zden;
        s_vz[v] = vz;
    }
    __syncthreads();

    // tile NDC bounds (px decreasing in x, py decreasing in y)
    const float pxmax = 1.0f - ((float)(tileX * 16) + 0.5f) * (1.0f / 64.0f);
    const float pxmin = 1.0f - ((float)(tileX * 16) + 15.5f) * (1.0f / 64.0f);
    const float pymax = 1.0f - ((float)(tileY * 16) + 0.5f) * (1.0f / 64.0f);
    const float pymin = 1.0f - ((float)(tileY * 16) + 15.5f) * (1.0f / 64.0f);
    const float MARG = 0.02f;  // validity needs dist < 0.01 NDC; 2x slop

    // ---------------- Phase 1: face records + bbox flags ----------------
    for (int f = tid; f < NFACE; f += 256) {
        int g = f >> 6, i = f & 63, rr = i >> 3, cc = i & 7;
        int ny = 2 * rr + (g >> 2);
        int oddx = ((g & 2) ? 0 : 1) ^ (g >> 2);
        int nx = 2 * cc + oddx;
        int p = g & 3;
        // vertex offset tables per pattern (p = g & 3); dx0=1, dx1=0 always
        const int dy0[4] = {0, 0, 0, 1};
        const int dy1[4] = {0, 1, 0, 0};
        const int dy2[4] = {1, 1, 1, 1};
        const int dx2[4] = {0, 1, 1, 0};
        int v0 = (ny + dy0[p]) * 17 + nx + 1;
        int v1 = (ny + dy1[p]) * 17 + nx;
        int v2 = (ny + dy2[p]) * 17 + nx + dx2[p];

        float ax = s_vx[v0], ay = s_vy[v0], z0 = s_vz[v0];
        float bx = s_vx[v1], by = s_vy[v1], z1 = s_vz[v1];
        float cx = s_vx[v2], cy = s_vy[v2], z2 = s_vz[v2];
        float* F = &s_f[f * 28];
        F[0] = ax; F[1] = ay; F[2] = bx; F[3] = by; F[4] = cx; F[5] = cy;
        float dabx = bx - ax, daby = by - ay;
        F[6] = dabx; F[7] = daby;
        F[8] = 1.0f / fmaxf(dabx * dabx + daby * daby, 1e-12f);
        float dbcx = cx - bx, dbcy = cy - by;
        F[9] = dbcx; F[10] = dbcy;
        F[11] = 1.0f / fmaxf(dbcx * dbcx + dbcy * dbcy, 1e-12f);
        float dcax = ax - cx, dcay = ay - cy;
        F[12] = dcax; F[13] = dcay;
        F[14] = 1.0f / fmaxf(dcax * dcax + dcay * dcay, 1e-12f);
        float area = dabx * (cy - ay) - daby * (cx - ax);
        float areas = (fabsf(area) < 1e-8f) ? 1e-8f : area;
        F[15] = 1.0f / areas;
        F[16] = z0; F[17] = z1; F[18] = z2;
        F[19] = z1 * z2; F[20] = z0 * z2; F[21] = z0 * z1;
        int ix0 = v0 % 17, iy0 = v0 / 17;
        int ix1 = v1 % 17, iy1 = v1 / 17;
        int ix2 = v2 % 17, iy2 = v2 / 17;
        F[22] = 1.0f - 0.0625f * (float)ix0; F[23] = 0.0625f * (float)iy0;
        F[24] = 1.0f - 0.0625f * (float)ix1; F[25] = 0.0625f * (float)iy1;
        F[26] = 1.0f - 0.0625f * (float)ix2; F[27] = 0.0625f * (float)iy2;

        float minx = fminf(ax, fminf(bx, cx)), maxx = fmaxf(ax, fmaxf(bx, cx));
        float miny = fminf(ay, fminf(by, cy)), maxy = fmaxf(ay, fmaxf(by, cy));
        bool ov = (minx - MARG <= pxmax) && (maxx + MARG >= pxmin) &&
                  (miny - MARG <= pymax) && (maxy + MARG >= pymin);
        s_flag[f] = ov ? 1 : 0;
    }
    __syncthreads();

    // ---------------- Phase 2: ordered compaction (wave 0) ----------------
    if (tid < 64) {
        int cnt = 0;
        for (int base = 0; base < NFACE; base += 64) {
            bool ov = s_flag[base + tid] != 0;
            unsigned long long mask = __ballot(ov);
            if (ov) {
                int pos = cnt + (int)__popcll(mask & ((1ull << tid) - 1ull));
                s_list[pos] = base + tid;
            }
            cnt += (int)__popcll(mask);
        }
        if (tid == 0) s_nf = cnt;
    }
    __syncthreads();

    // ---------------- Phase 3: per-pixel top-8 ----------------
    const int lane = tid & 63, wv = tid >> 6;
    const int x = tileX * 16 + ((wv & 1) << 3) + (lane & 7);
    const int y = tileY * 16 + ((wv >> 1) << 3) + (lane >> 3);
    const float px = 1.0f - ((float)x + 0.5f) * (1.0f / 64.0f);
    const float py = 1.0f - ((float)y + 0.5f) * (1.0f / 64.0f);

    float kk[8], dd[8];
    int ii[8];
#pragma unroll
    for (int j = 0; j < 8; ++j) { kk[j] = __builtin_inff(); dd[j] = 0.0f; ii[j] = -1; }

    const int nf = s_nf;
    for (int i = 0; i < nf; ++i) {
        const int ci = s_list[i];
        const float4* Fp = (const float4*)(&s_f[ci * 28]);
        const float4 f0 = Fp[0], f1 = Fp[1], f2 = Fp[2], f3 = Fp[3];
        const float ax = f0.x, ay = f0.y, bx = f0.z, by = f0.w, cx = f1.x, cy = f1.y;
        // min squared distance to the 3 edge segments
        float t, ex, ey, d2;
        t = ((px - ax) * f1.z + (py - ay) * f1.w) * f2.x;
        t = fminf(fmaxf(t, 0.0f), 1.0f);
        ex = px - (ax + t * f1.z); ey = py - (ay + t * f1.w);
        d2 = ex * ex + ey * ey;
        t = ((px - bx) * f2.y + (py - by) * f2.z) * f2.w;
        t = fminf(fmaxf(t, 0.0f), 1.0f);
        ex = px - (bx + t * f2.y); ey = py - (by + t * f2.z);
        d2 = fminf(d2, ex * ex + ey * ey);
        t = ((px - cx) * f3.x + (py - cy) * f3.y) * f3.z;
        t = fminf(fmaxf(t, 0.0f), 1.0f);
        ex = px - (cx + t * f3.x); ey = py - (cy + t * f3.y);
        d2 = fminf(d2, ex * ex + ey * ey);
        // edge functions / signed barycentrics
        float w0 = (bx - px) * (cy - py) - (by - py) * (cx - px);
        float w1 = (cx - px) * (ay - py) - (cy - py) * (ax - px);
        float w2 = (ax - px) * (by - py) - (ay - py) * (bx - px);
        float b0 = w0 * f3.w, b1 = w1 * f3.w, b2 = w2 * f3.w;
        bool inside = (b0 >= 0.0f) && (b1 >= 0.0f) && (b2 >= 0.0f);
        float sd = inside ? -d2 : d2;
        if (sd < 1e-4f) {
            const float4 f4 = Fp[4], f5 = Fp[5];
            float n0 = b0 * f4.w, n1 = b1 * f5.x, n2 = b2 * f5.y;
            float den = n0 + n1 + n2;
            den = (fabsf(den) < 1e-10f) ? 1e-10f : den;
            float c0 = fmaxf(n0 / den, 0.0f);
            float c1 = fmaxf(n1 / den, 0.0f);
            float c2 = fmaxf(n2 / den, 0.0f);
            float scn = fmaxf(c0 + c1 + c2, 1e-10f);
            float zp = (c0 * f4.x + c1 * f4.y + c2 * f4.z) / scn;
            if (zp > 1e-4f && zp < kk[7]) {
                // predicated insertion into sorted-by-z top-8
#pragma unroll
                for (int j = 7; j >= 1; --j) {
                    bool m1 = zp < kk[j];
                    bool m2 = zp < kk[j - 1];
                    kk[j] = m1 ? (m2 ? kk[j - 1] : zp) : kk[j];
                    dd[j] = m1 ? (m2 ? dd[j - 1] : sd) : dd[j];
                    ii[j] = m1 ? (m2 ? ii[j - 1] : ci) : ii[j];
                }
                if (zp < kk[0]) { kk[0] = zp; dd[0] = sd; ii[0] = ci; }
            }
        }
    }

    // ---------------- Phase 4: shade + online-softmax aggregate ----------------
    float m_ = 1e-10f, S = 0.0f, aR = 0.0f, aG = 0.0f, aB = 0.0f, aD = 0.0f;
    float om = 1.0f;
#pragma unroll
    for (int j = 0; j < 8; ++j) {
        const int ci = ii[j];
        if (ci >= 0) {
            const float4* Fp = (const float4*)(&s_f[ci * 28]);
            const float4 f0 = Fp[0], f1 = Fp[1], f3 = Fp[3], f4 = Fp[4], f5 = Fp[5], f6 = Fp[6];
            const float ax = f0.x, ay = f0.y, bx = f0.z, by = f0.w, cx = f1.x, cy = f1.y;
            float w0 = (bx - px) * (cy - py) - (by - py) * (cx - px);
            float w1 = (cx - px) * (ay - py) - (cy - py) * (ax - px);
            float w2 = (ax - px) * (by - py) - (ay - py) * (bx - px);
            float b0 = w0 * f3.w, b1 = w1 * f3.w, b2 = w2 * f3.w;
            float n0 = b0 * f4.w, n1 = b1 * f5.x, n2 = b2 * f5.y;
            float den = n0 + n1 + n2;
            den = (fabsf(den) < 1e-10f) ? 1e-10f : den;
            float c0 = fmaxf(n0 / den, 0.0f);
            float c1 = fmaxf(n1 / den, 0.0f);
            float c2 = fmaxf(n2 / den, 0.0f);
            float scn = fmaxf(c0 + c1 + c2, 1e-10f);
            float bc0 = c0 / scn, bc1 = c1 / scn, bc2 = c2 / scn;
            float u = bc0 * f5.z + bc1 * f6.x + bc2 * f6.z;
            float v = bc0 * f5.w + bc1 * f6.y + bc2 * f6.w;
            float tx = u * 127.0f;
            float ty = (1.0f - v) * 127.0f;
            float x0f = fminf(fmaxf(floorf(tx), 0.0f), 127.0f);
            float y0f = fminf(fmaxf(floorf(ty), 0.0f), 127.0f);
            int x0 = (int)x0f, y0 = (int)y0f;
            int x1 = (x0 + 1 < 127) ? x0 + 1 : 127;
            int y1 = (y0 + 1 < 127) ? y0 + 1 : 127;
            float wx = tx - x0f, wy = ty - y0f;
            const float* t00 = texd + (y0 * 128 + x0) * 3;
            const float* t01 = texd + (y0 * 128 + x1) * 3;
            const float* t10 = texd + (y1 * 128 + x0) * 3;
            const float* t11 = texd + (y1 * 128 + x1) * 3;
            float r  = (1.0f - wy) * ((1.0f - wx) * t00[0] + wx * t01[0]) + wy * ((1.0f - wx) * t10[0] + wx * t11[0]);
            float gc = (1.0f - wy) * ((1.0f - wx) * t00[1] + wx * t01[1]) + wy * ((1.0f - wx) * t10[1] + wx * t11[1]);
            float bc = (1.0f - wy) * ((1.0f - wx) * t00[2] + wx * t01[2]) + wy * ((1.0f - wx) * t10[2] + wx * t11[2]);
            float prob = 1.0f / (1.0f + expf(dd[j] / 1e-4f));  // sigmoid(-sd/SIGMA)
            float zk = kk[j];
            float zi = (100.0f - zk) / 99.0f;
            om *= (1.0f - prob);
            if (zi > m_) {
                float scl = expf((m_ - zi) / 1e-4f);
                S *= scl; aR *= scl; aG *= scl; aB *= scl; aD *= scl;
                m_ = zi;
            }
            float wgt = prob * expf((zi - m_) / 1e-4f);
            S += wgt; aR += wgt * r; aG += wgt * gc; aB += wgt * bc; aD += wgt * zk;
        }
    }
    float delta = expf((1e-10f - m_) / 1e-4f);
    S += delta;
    aD += delta * 100.0f;  // Z_BACKGROUND
    float invS = 1.0f / S;
    const int o = (y * 128 + x) * 5;
    out[o + 0] = aR * invS;
    out[o + 1] = aG * invS;
    out[o + 2] = aB * invS;
    out[o + 3] = 1.0f - om;
    out[o + 4] = aD * invS;
}

extern "C" void kernel_launch(void* const* d_in, const int* in_sizes, int n_in,
                              void* d_out, int out_size, void* d_ws, size_t ws_size,
                              hipStream_t stream) {
    const float* xy_off = (const float*)d_in[0];
    const float* zg     = (const float*)d_in[1];
    const float* rgb    = (const float*)d_in[2];
    const float* R_in   = (const float*)d_in[3];
    const float* T_in   = (const float*)d_in[4];
    const float* R_out  = (const float*)d_in[5];
    const float* T_out  = (const float*)d_in[6];
    float* out = (float*)d_out;
    nvp_kernel<<<dim3(64), dim3(256), 0, stream>>>(xy_off, zg, rgb, R_in, T_in,
                                                   R_out, T_out, out);
}

// Round 2
// 80.305 us; speedup vs baseline: 1.1267x; 1.1267x over previous
//
#include <hip/hip_runtime.h>
#include <math.h>

#define NVERT 289
#define NFACE 512

// 256 blocks: one 8x8-pixel tile per CU. 256 threads: 4 slices x 64 pixels.
// Each block: verts -> LDS, all-face setup -> LDS, bbox binning, 4-way split
// face loop with per-slice top-8, LDS merge, shade by wave 0.
__global__ __launch_bounds__(256) void nvp_kernel(
    const float* __restrict__ xy_off,
    const float* __restrict__ z_grid,
    const float* __restrict__ texd,
    const float* __restrict__ R_in,
    const float* __restrict__ T_in,
    const float* __restrict__ R_out,
    const float* __restrict__ T_out,
    float* __restrict__ out)
{
    __shared__ __align__(16) float s_f[NFACE * 28];
    __shared__ float s_vx[NVERT], s_vy[NVERT], s_vz[NVERT];
    __shared__ unsigned char s_flag[NFACE];
    __shared__ int s_list[NFACE];
    __shared__ int s_nf;
    // per-slice top-8: [slice][pixel][slot], slot dim padded to 9
    __shared__ float s_tz[4][64][9];
    __shared__ float s_td[4][64][9];
    __shared__ int   s_ti[4][64][9];

    const int tid = threadIdx.x;
    const int tileX = blockIdx.x & 15;
    const int tileY = blockIdx.x >> 4;

    const float SC = 0.57735026918962576f;        // tan(30 deg)
    const float SI = 1.0f / 0.57735026918962576f; // 1/SCALE

    // ---------------- Phase 0: screen-space vertices ----------------
    for (int v = tid; v < NVERT; v += 256) {
        int ix = v % 17, iy = v / 17;
        float gx = -1.0f + 0.125f * (float)ix;
        float gy = -1.0f + 0.125f * (float)iy;
        float sx = (gx + xy_off[2 * v]) * SC;
        float sy = (gy + xy_off[2 * v + 1]) * SC;
        float z = z_grid[v];
        float X = sx * z, Y = sy * z, Z = z;
        float p0 = X - T_in[0], p1 = Y - T_in[1], p2 = Z - T_in[2];
        float wxx = R_in[0] * p0 + R_in[1] * p1 + R_in[2] * p2;
        float wyy = R_in[3] * p0 + R_in[4] * p1 + R_in[5] * p2;
        float wzz = R_in[6] * p0 + R_in[7] * p1 + R_in[8] * p2;
        float vx = wxx * R_out[0] + wyy * R_out[3] + wzz * R_out[6] + T_out[0];
        float vy = wxx * R_out[1] + wyy * R_out[4] + wzz * R_out[7] + T_out[1];
        float vz = wxx * R_out[2] + wyy * R_out[5] + wzz * R_out[8] + T_out[2];
        float zden = (vz >= 0.0f) ? fmaxf(vz, 0.01f) : fminf(vz, -0.01f);
        s_vx[v] = SI * vx / zden;
        s_vy[v] = SI * vy / zden;
        s_vz[v] = vz;
    }
    __syncthreads();

    // tile NDC bounds (px decreasing in x, py decreasing in y); 8px tile
    const float pxmax = 1.0f - ((float)(tileX * 8) + 0.5f) * (1.0f / 64.0f);
    const float pxmin = 1.0f - ((float)(tileX * 8) + 7.5f) * (1.0f / 64.0f);
    const float pymax = 1.0f - ((float)(tileY * 8) + 0.5f) * (1.0f / 64.0f);
    const float pymin = 1.0f - ((float)(tileY * 8) + 7.5f) * (1.0f / 64.0f);
    const float MARG = 0.015f;  // validity needs edge-dist < 0.01 NDC

    // ---------------- Phase 1: face records + bbox flags ----------------
    for (int f = tid; f < NFACE; f += 256) {
        int g = f >> 6, i = f & 63, rr = i >> 3, cc = i & 7;
        int ny = 2 * rr + (g >> 2);
        int oddx = ((g & 2) ? 0 : 1) ^ (g >> 2);
        int nx = 2 * cc + oddx;
        int p = g & 3;
        const int dy0[4] = {0, 0, 0, 1};
        const int dy1[4] = {0, 1, 0, 0};
        const int dy2[4] = {1, 1, 1, 1};
        const int dx2[4] = {0, 1, 1, 0};
        int v0 = (ny + dy0[p]) * 17 + nx + 1;
        int v1 = (ny + dy1[p]) * 17 + nx;
        int v2 = (ny + dy2[p]) * 17 + nx + dx2[p];

        float ax = s_vx[v0], ay = s_vy[v0], z0 = s_vz[v0];
        float bx = s_vx[v1], by = s_vy[v1], z1 = s_vz[v1];
        float cx = s_vx[v2], cy = s_vy[v2], z2 = s_vz[v2];
        float* F = &s_f[f * 28];
        F[0] = ax; F[1] = ay; F[2] = bx; F[3] = by; F[4] = cx; F[5] = cy;
        float dabx = bx - ax, daby = by - ay;
        F[6] = dabx; F[7] = daby;
        F[8] = 1.0f / fmaxf(dabx * dabx + daby * daby, 1e-12f);
        float dbcx = cx - bx, dbcy = cy - by;
        F[9] = dbcx; F[10] = dbcy;
        F[11] = 1.0f / fmaxf(dbcx * dbcx + dbcy * dbcy, 1e-12f);
        float dcax = ax - cx, dcay = ay - cy;
        F[12] = dcax; F[13] = dcay;
        F[14] = 1.0f / fmaxf(dcax * dcax + dcay * dcay, 1e-12f);
        float area = dabx * (cy - ay) - daby * (cx - ax);
        float areas = (fabsf(area) < 1e-8f) ? 1e-8f : area;
        F[15] = 1.0f / areas;
        F[16] = z0; F[17] = z1; F[18] = z2;
        F[19] = z1 * z2; F[20] = z0 * z2; F[21] = z0 * z1;
        int ix0 = v0 % 17, iy0 = v0 / 17;
        int ix1 = v1 % 17, iy1 = v1 / 17;
        int ix2 = v2 % 17, iy2 = v2 / 17;
        F[22] = 1.0f - 0.0625f * (float)ix0; F[23] = 0.0625f * (float)iy0;
        F[24] = 1.0f - 0.0625f * (float)ix1; F[25] = 0.0625f * (float)iy1;
        F[26] = 1.0f - 0.0625f * (float)ix2; F[27] = 0.0625f * (float)iy2;

        float minx = fminf(ax, fminf(bx, cx)), maxx = fmaxf(ax, fmaxf(bx, cx));
        float miny = fminf(ay, fminf(by, cy)), maxy = fmaxf(ay, fmaxf(by, cy));
        bool ov = (minx - MARG <= pxmax) && (maxx + MARG >= pxmin) &&
                  (miny - MARG <= pymax) && (maxy + MARG >= pymin);
        s_flag[f] = ov ? 1 : 0;
    }
    __syncthreads();

    // ---------------- Phase 2: ordered compaction (wave 0) ----------------
    if (tid < 64) {
        int cnt = 0;
        for (int base = 0; base < NFACE; base += 64) {
            bool ov = s_flag[base + tid] != 0;
            unsigned long long mask = __ballot(ov);
            if (ov) {
                int pos = cnt + (int)__popcll(mask & ((1ull << tid) - 1ull));
                s_list[pos] = base + tid;
            }
            cnt += (int)__popcll(mask);
        }
        if (tid == 0) s_nf = cnt;
    }
    __syncthreads();

    // ---------------- Phase 3: 4-way split per-pixel top-8 ----------------
    const int p = tid & 63;       // pixel within tile
    const int sl = tid >> 6;      // slice (which quarter of the face list)
    const int x = tileX * 8 + (p & 7);
    const int y = tileY * 8 + (p >> 3);
    const float px = 1.0f - ((float)x + 0.5f) * (1.0f / 64.0f);
    const float py = 1.0f - ((float)y + 0.5f) * (1.0f / 64.0f);

    float kk[8], dd[8];
    int ii[8];
#pragma unroll
    for (int j = 0; j < 8; ++j) { kk[j] = __builtin_inff(); dd[j] = 0.0f; ii[j] = -1; }

    const int nf = s_nf;
    for (int i = sl; i < nf; i += 4) {
        const int ci = s_list[i];
        const float4* Fp = (const float4*)(&s_f[ci * 28]);
        const float4 f0 = Fp[0], f1 = Fp[1], f2 = Fp[2], f3 = Fp[3];
        const float ax = f0.x, ay = f0.y, bx = f0.z, by = f0.w, cx = f1.x, cy = f1.y;
        float t, ex, ey, d2;
        t = ((px - ax) * f1.z + (py - ay) * f1.w) * f2.x;
        t = fminf(fmaxf(t, 0.0f), 1.0f);
        ex = px - (ax + t * f1.z); ey = py - (ay + t * f1.w);
        d2 = ex * ex + ey * ey;
        t = ((px - bx) * f2.y + (py - by) * f2.z) * f2.w;
        t = fminf(fmaxf(t, 0.0f), 1.0f);
        ex = px - (bx + t * f2.y); ey = py - (by + t * f2.z);
        d2 = fminf(d2, ex * ex + ey * ey);
        t = ((px - cx) * f3.x + (py - cy) * f3.y) * f3.z;
        t = fminf(fmaxf(t, 0.0f), 1.0f);
        ex = px - (cx + t * f3.x); ey = py - (cy + t * f3.y);
        d2 = fminf(d2, ex * ex + ey * ey);
        float w0 = (bx - px) * (cy - py) - (by - py) * (cx - px);
        float w1 = (cx - px) * (ay - py) - (cy - py) * (ax - px);
        float w2 = (ax - px) * (by - py) - (ay - py) * (bx - px);
        float b0 = w0 * f3.w, b1 = w1 * f3.w, b2 = w2 * f3.w;
        bool inside = (b0 >= 0.0f) && (b1 >= 0.0f) && (b2 >= 0.0f);
        float sd = inside ? -d2 : d2;
        if (sd < 1e-4f) {
            const float4 f4 = Fp[4], f5 = Fp[5];
            float n0 = b0 * f4.w, n1 = b1 * f5.x, n2 = b2 * f5.y;
            float den = n0 + n1 + n2;
            den = (fabsf(den) < 1e-10f) ? 1e-10f : den;
            float c0 = fmaxf(n0 / den, 0.0f);
            float c1 = fmaxf(n1 / den, 0.0f);
            float c2 = fmaxf(n2 / den, 0.0f);
            float scn = fmaxf(c0 + c1 + c2, 1e-10f);
            float zp = (c0 * f4.x + c1 * f4.y + c2 * f4.z) / scn;
            if (zp > 1e-4f && zp < kk[7]) {
#pragma unroll
                for (int j = 7; j >= 1; --j) {
                    bool m1 = zp < kk[j];
                    bool m2 = zp < kk[j - 1];
                    kk[j] = m1 ? (m2 ? kk[j - 1] : zp) : kk[j];
                    dd[j] = m1 ? (m2 ? dd[j - 1] : sd) : dd[j];
                    ii[j] = m1 ? (m2 ? ii[j - 1] : ci) : ii[j];
                }
                if (zp < kk[0]) { kk[0] = zp; dd[0] = sd; ii[0] = ci; }
            }
        }
    }

    // publish per-slice sorted top-8
#pragma unroll
    for (int j = 0; j < 8; ++j) {
        s_tz[sl][p][j] = kk[j];
        s_td[sl][p][j] = dd[j];
        s_ti[sl][p][j] = ii[j];
    }
    __syncthreads();

    // ---------------- Phase 4: merge + shade (wave 0) ----------------
    if (tid < 64) {
        // 4-way merge of sorted lists -> global top-8
        int h0 = 0, h1 = 0, h2 = 0, h3 = 0;
        float z0h = s_tz[0][tid][0], z1h = s_tz[1][tid][0];
        float z2h = s_tz[2][tid][0], z3h = s_tz[3][tid][0];
        float mk[8], md[8];
        int mi[8];
#pragma unroll
        for (int j = 0; j < 8; ++j) {
            // argmin over 4 heads
            int s01 = (z1h < z0h) ? 1 : 0;
            float za = fminf(z0h, z1h);
            int s23 = (z3h < z2h) ? 3 : 2;
            float zb = fminf(z2h, z3h);
            int sw = (zb < za) ? s23 : s01;
            float zw = fminf(za, zb);
            mk[j] = zw;
            if (sw == 0)      { md[j] = s_td[0][tid][h0]; mi[j] = s_ti[0][tid][h0]; ++h0; z0h = (h0 < 8) ? s_tz[0][tid][h0] : __builtin_inff(); }
            else if (sw == 1) { md[j] = s_td[1][tid][h1]; mi[j] = s_ti[1][tid][h1]; ++h1; z1h = (h1 < 8) ? s_tz[1][tid][h1] : __builtin_inff(); }
            else if (sw == 2) { md[j] = s_td[2][tid][h2]; mi[j] = s_ti[2][tid][h2]; ++h2; z2h = (h2 < 8) ? s_tz[2][tid][h2] : __builtin_inff(); }
            else              { md[j] = s_td[3][tid][h3]; mi[j] = s_ti[3][tid][h3]; ++h3; z3h = (h3 < 8) ? s_tz[3][tid][h3] : __builtin_inff(); }
        }

        float m_ = 1e-10f, S = 0.0f, aR = 0.0f, aG = 0.0f, aB = 0.0f, aD = 0.0f;
        float om = 1.0f;
#pragma unroll
        for (int j = 0; j < 8; ++j) {
            const int ci = mi[j];
            if (ci >= 0) {
                const float4* Fp = (const float4*)(&s_f[ci * 28]);
                const float4 f0 = Fp[0], f1 = Fp[1], f3 = Fp[3], f4 = Fp[4], f5 = Fp[5], f6 = Fp[6];
                const float ax = f0.x, ay = f0.y, bx = f0.z, by = f0.w, cx = f1.x, cy = f1.y;
                float w0 = (bx - px) * (cy - py) - (by - py) * (cx - px);
                float w1 = (cx - px) * (ay - py) - (cy - py) * (ax - px);
                float w2 = (ax - px) * (by - py) - (ay - py) * (bx - px);
                float b0 = w0 * f3.w, b1 = w1 * f3.w, b2 = w2 * f3.w;
                float n0 = b0 * f4.w, n1 = b1 * f5.x, n2 = b2 * f5.y;
                float den = n0 + n1 + n2;
                den = (fabsf(den) < 1e-10f) ? 1e-10f : den;
                float c0 = fmaxf(n0 / den, 0.0f);
                float c1 = fmaxf(n1 / den, 0.0f);
                float c2 = fmaxf(n2 / den, 0.0f);
                float scn = fmaxf(c0 + c1 + c2, 1e-10f);
                float bc0 = c0 / scn, bc1 = c1 / scn, bc2 = c2 / scn;
                float u = bc0 * f5.z + bc1 * f6.x + bc2 * f6.z;
                float v = bc0 * f5.w + bc1 * f6.y + bc2 * f6.w;
                float tx = u * 127.0f;
                float ty = (1.0f - v) * 127.0f;
                float x0f = fminf(fmaxf(floorf(tx), 0.0f), 127.0f);
                float y0f = fminf(fmaxf(floorf(ty), 0.0f), 127.0f);
                int x0 = (int)x0f, y0 = (int)y0f;
                int x1 = (x0 + 1 < 127) ? x0 + 1 : 127;
                int y1 = (y0 + 1 < 127) ? y0 + 1 : 127;
                float wx = tx - x0f, wy = ty - y0f;
                const float* t00 = texd + (y0 * 128 + x0) * 3;
                const float* t01 = texd + (y0 * 128 + x1) * 3;
                const float* t10 = texd + (y1 * 128 + x0) * 3;
                const float* t11 = texd + (y1 * 128 + x1) * 3;
                float r  = (1.0f - wy) * ((1.0f - wx) * t00[0] + wx * t01[0]) + wy * ((1.0f - wx) * t10[0] + wx * t11[0]);
                float gc = (1.0f - wy) * ((1.0f - wx) * t00[1] + wx * t01[1]) + wy * ((1.0f - wx) * t10[1] + wx * t11[1]);
                float bc = (1.0f - wy) * ((1.0f - wx) * t00[2] + wx * t01[2]) + wy * ((1.0f - wx) * t10[2] + wx * t11[2]);
                float prob = 1.0f / (1.0f + expf(md[j] / 1e-4f));  // sigmoid(-sd/SIGMA)
                float zk = mk[j];
                float zi = (100.0f - zk) / 99.0f;
                om *= (1.0f - prob);
                if (zi > m_) {
                    float scl = expf((m_ - zi) / 1e-4f);
                    S *= scl; aR *= scl; aG *= scl; aB *= scl; aD *= scl;
                    m_ = zi;
                }
                float wgt = prob * expf((zi - m_) / 1e-4f);
                S += wgt; aR += wgt * r; aG += wgt * gc; aB += wgt * bc; aD += wgt * zk;
            }
        }
        float delta = expf((1e-10f - m_) / 1e-4f);
        S += delta;
        aD += delta * 100.0f;  // Z_BACKGROUND
        float invS = 1.0f / S;
        const int o = (y * 128 + x) * 5;
        out[o + 0] = aR * invS;
        out[o + 1] = aG * invS;
        out[o + 2] = aB * invS;
        out[o + 3] = 1.0f - om;
        out[o + 4] = aD * invS;
    }
}

extern "C" void kernel_launch(void* const* d_in, const int* in_sizes, int n_in,
                              void* d_out, int out_size, void* d_ws, size_t ws_size,
                              hipStream_t stream) {
    const float* xy_off = (const float*)d_in[0];
    const float* zg     = (const float*)d_in[1];
    const float* rgb    = (const float*)d_in[2];
    const float* R_in   = (const float*)d_in[3];
    const float* T_in   = (const float*)d_in[4];
    const float* R_out  = (const float*)d_in[5];
    const float* T_out  = (const float*)d_in[6];
    float* out = (float*)d_out;
    nvp_kernel<<<dim3(256), dim3(256), 0, stream>>>(xy_off, zg, rgb, R_in, T_in,
                                                    R_out, T_out, out);
}

// Round 3
// 76.940 us; speedup vs baseline: 1.1760x; 1.0437x over previous
//
#include <hip/hip_runtime.h>
#include <math.h>

#define NVERT 289
#define NFACE 512
#define MAXB 128   // max binned faces per 8x8 tile (analysis: ~10-16 typical)

// Decode face f -> vertex indices (matches _build_faces ordering).
__device__ __forceinline__ void face_verts(int f, int& v0, int& v1, int& v2) {
    int g = f >> 6, i = f & 63, rr = i >> 3, cc = i & 7;
    int ny = 2 * rr + (g >> 2);
    int oddx = ((g & 2) ? 0 : 1) ^ (g >> 2);
    int nx = 2 * cc + oddx;
    int p = g & 3;
    const int dy0[4] = {0, 0, 0, 1};
    const int dy1[4] = {0, 1, 0, 0};
    const int dx2[4] = {0, 1, 1, 0};
    v0 = (ny + dy0[p]) * 17 + nx + 1;
    v1 = (ny + dy1[p]) * 17 + nx;
    v2 = (ny + 1) * 17 + nx + dx2[p];
}

// 256 blocks: one 8x8-pixel tile per CU. 256 threads: 4 slices x 64 pixels.
// Deferred face setup: bbox-flag all 512 faces cheaply, compact, then build
// full 28-float records ONLY for the ~12 binned faces (compacted storage).
__global__ __launch_bounds__(256) void nvp_kernel(
    const float* __restrict__ xy_off,
    const float* __restrict__ z_grid,
    const float* __restrict__ texd,
    const float* __restrict__ R_in,
    const float* __restrict__ T_in,
    const float* __restrict__ R_out,
    const float* __restrict__ T_out,
    float* __restrict__ out)
{
    __shared__ __align__(16) float s_f[MAXB * 28];
    __shared__ float s_vx[NVERT], s_vy[NVERT], s_vz[NVERT];
    __shared__ unsigned char s_flag[NFACE];
    __shared__ int s_list[MAXB];
    __shared__ int s_nf;
    __shared__ float s_tz[4][64][9];
    __shared__ float s_td[4][64][9];
    __shared__ int   s_ti[4][64][9];

    const int tid = threadIdx.x;
    const int tileX = blockIdx.x & 15;
    const int tileY = blockIdx.x >> 4;

    const float SC = 0.57735026918962576f;        // tan(30 deg)
    const float SI = 1.0f / 0.57735026918962576f; // 1/SCALE

    // ---------------- Phase 0: screen-space vertices ----------------
    for (int v = tid; v < NVERT; v += 256) {
        int ix = v % 17, iy = v / 17;
        float gx = -1.0f + 0.125f * (float)ix;
        float gy = -1.0f + 0.125f * (float)iy;
        float sx = (gx + xy_off[2 * v]) * SC;
        float sy = (gy + xy_off[2 * v + 1]) * SC;
        float z = z_grid[v];
        float X = sx * z, Y = sy * z, Z = z;
        float p0 = X - T_in[0], p1 = Y - T_in[1], p2 = Z - T_in[2];
        float wxx = R_in[0] * p0 + R_in[1] * p1 + R_in[2] * p2;
        float wyy = R_in[3] * p0 + R_in[4] * p1 + R_in[5] * p2;
        float wzz = R_in[6] * p0 + R_in[7] * p1 + R_in[8] * p2;
        float vx = wxx * R_out[0] + wyy * R_out[3] + wzz * R_out[6] + T_out[0];
        float vy = wxx * R_out[1] + wyy * R_out[4] + wzz * R_out[7] + T_out[1];
        float vz = wxx * R_out[2] + wyy * R_out[5] + wzz * R_out[8] + T_out[2];
        float zden = (vz >= 0.0f) ? fmaxf(vz, 0.01f) : fminf(vz, -0.01f);
        s_vx[v] = SI * vx / zden;
        s_vy[v] = SI * vy / zden;
        s_vz[v] = vz;
    }
    __syncthreads();

    // tile NDC bounds (px decreasing in x, py decreasing in y); 8px tile
    const float pxmax = 1.0f - ((float)(tileX * 8) + 0.5f) * (1.0f / 64.0f);
    const float pxmin = 1.0f - ((float)(tileX * 8) + 7.5f) * (1.0f / 64.0f);
    const float pymax = 1.0f - ((float)(tileY * 8) + 0.5f) * (1.0f / 64.0f);
    const float pymin = 1.0f - ((float)(tileY * 8) + 7.5f) * (1.0f / 64.0f);
    const float MARG = 0.015f;  // validity needs edge-dist < 0.01 NDC

    // ---------------- Phase 1a: cheap bbox flags only ----------------
    for (int f = tid; f < NFACE; f += 256) {
        int v0, v1, v2;
        face_verts(f, v0, v1, v2);
        float ax = s_vx[v0], ay = s_vy[v0];
        float bx = s_vx[v1], by = s_vy[v1];
        float cx = s_vx[v2], cy = s_vy[v2];
        float minx = fminf(ax, fminf(bx, cx)), maxx = fmaxf(ax, fmaxf(bx, cx));
        float miny = fminf(ay, fminf(by, cy)), maxy = fmaxf(ay, fmaxf(by, cy));
        bool ov = (minx - MARG <= pxmax) && (maxx + MARG >= pxmin) &&
                  (miny - MARG <= pymax) && (maxy + MARG >= pymin);
        s_flag[f] = ov ? 1 : 0;
    }
    __syncthreads();

    // ---------------- Phase 2: ordered compaction (wave 0) ----------------
    if (tid < 64) {
        int cnt = 0;
        for (int base = 0; base < NFACE; base += 64) {
            bool ov = s_flag[base + tid] != 0;
            unsigned long long mask = __ballot(ov);
            if (ov) {
                int pos = cnt + (int)__popcll(mask & ((1ull << tid) - 1ull));
                if (pos < MAXB) s_list[pos] = base + tid;
            }
            cnt += (int)__popcll(mask);
        }
        if (tid == 0) s_nf = (cnt < MAXB) ? cnt : MAXB;
    }
    __syncthreads();

    const int nf = s_nf;

    // ---------------- Phase 1b: full records for binned faces only ----------
    if (tid < nf) {
        int f = s_list[tid];
        int v0, v1, v2;
        face_verts(f, v0, v1, v2);
        float ax = s_vx[v0], ay = s_vy[v0], z0 = s_vz[v0];
        float bx = s_vx[v1], by = s_vy[v1], z1 = s_vz[v1];
        float cx = s_vx[v2], cy = s_vy[v2], z2 = s_vz[v2];
        float* F = &s_f[tid * 28];
        F[0] = ax; F[1] = ay; F[2] = bx; F[3] = by; F[4] = cx; F[5] = cy;
        float dabx = bx - ax, daby = by - ay;
        F[6] = dabx; F[7] = daby;
        F[8] = 1.0f / fmaxf(dabx * dabx + daby * daby, 1e-12f);
        float dbcx = cx - bx, dbcy = cy - by;
        F[9] = dbcx; F[10] = dbcy;
        F[11] = 1.0f / fmaxf(dbcx * dbcx + dbcy * dbcy, 1e-12f);
        float dcax = ax - cx, dcay = ay - cy;
        F[12] = dcax; F[13] = dcay;
        F[14] = 1.0f / fmaxf(dcax * dcax + dcay * dcay, 1e-12f);
        float area = dabx * (cy - ay) - daby * (cx - ax);
        float areas = (fabsf(area) < 1e-8f) ? 1e-8f : area;
        F[15] = 1.0f / areas;
        F[16] = z0; F[17] = z1; F[18] = z2;
        F[19] = z1 * z2; F[20] = z0 * z2; F[21] = z0 * z1;
        int ix0 = v0 % 17, iy0 = v0 / 17;
        int ix1 = v1 % 17, iy1 = v1 / 17;
        int ix2 = v2 % 17, iy2 = v2 / 17;
        F[22] = 1.0f - 0.0625f * (float)ix0; F[23] = 0.0625f * (float)iy0;
        F[24] = 1.0f - 0.0625f * (float)ix1; F[25] = 0.0625f * (float)iy1;
        F[26] = 1.0f - 0.0625f * (float)ix2; F[27] = 0.0625f * (float)iy2;
    }
    __syncthreads();

    // ---------------- Phase 3: 4-way split per-pixel top-8 ----------------
    const int p = tid & 63;       // pixel within tile
    const int sl = tid >> 6;      // slice
    const int x = tileX * 8 + (p & 7);
    const int y = tileY * 8 + (p >> 3);
    const float px = 1.0f - ((float)x + 0.5f) * (1.0f / 64.0f);
    const float py = 1.0f - ((float)y + 0.5f) * (1.0f / 64.0f);

    float kk[8], dd[8];
    int ii[8];
#pragma unroll
    for (int j = 0; j < 8; ++j) { kk[j] = __builtin_inff(); dd[j] = 0.0f; ii[j] = -1; }

    for (int i = sl; i < nf; i += 4) {
        const float4* Fp = (const float4*)(&s_f[i * 28]);
        const float4 f0 = Fp[0], f1 = Fp[1], f2 = Fp[2], f3 = Fp[3];
        const float ax = f0.x, ay = f0.y, bx = f0.z, by = f0.w, cx = f1.x, cy = f1.y;
        float t, ex, ey, d2;
        t = ((px - ax) * f1.z + (py - ay) * f1.w) * f2.x;
        t = fminf(fmaxf(t, 0.0f), 1.0f);
        ex = px - (ax + t * f1.z); ey = py - (ay + t * f1.w);
        d2 = ex * ex + ey * ey;
        t = ((px - bx) * f2.y + (py - by) * f2.z) * f2.w;
        t = fminf(fmaxf(t, 0.0f), 1.0f);
        ex = px - (bx + t * f2.y); ey = py - (by + t * f2.z);
        d2 = fminf(d2, ex * ex + ey * ey);
        t = ((px - cx) * f3.x + (py - cy) * f3.y) * f3.z;
        t = fminf(fmaxf(t, 0.0f), 1.0f);
        ex = px - (cx + t * f3.x); ey = py - (cy + t * f3.y);
        d2 = fminf(d2, ex * ex + ey * ey);
        float w0 = (bx - px) * (cy - py) - (by - py) * (cx - px);
        float w1 = (cx - px) * (ay - py) - (cy - py) * (ax - px);
        float w2 = (ax - px) * (by - py) - (ay - py) * (bx - px);
        float b0 = w0 * f3.w, b1 = w1 * f3.w, b2 = w2 * f3.w;
        bool inside = (b0 >= 0.0f) && (b1 >= 0.0f) && (b2 >= 0.0f);
        float sd = inside ? -d2 : d2;
        if (sd < 1e-4f) {
            const float4 f4 = Fp[4], f5 = Fp[5];
            float n0 = b0 * f4.w, n1 = b1 * f5.x, n2 = b2 * f5.y;
            float den = n0 + n1 + n2;
            den = (fabsf(den) < 1e-10f) ? 1e-10f : den;
            float iden = 1.0f / den;
            float c0 = fmaxf(n0 * iden, 0.0f);
            float c1 = fmaxf(n1 * iden, 0.0f);
            float c2 = fmaxf(n2 * iden, 0.0f);
            float iscn = 1.0f / fmaxf(c0 + c1 + c2, 1e-10f);
            float zp = (c0 * f4.x + c1 * f4.y + c2 * f4.z) * iscn;
            if (zp > 1e-4f && zp < kk[7]) {
#pragma unroll
                for (int j = 7; j >= 1; --j) {
                    bool m1 = zp < kk[j];
                    bool m2 = zp < kk[j - 1];
                    kk[j] = m1 ? (m2 ? kk[j - 1] : zp) : kk[j];
                    dd[j] = m1 ? (m2 ? dd[j - 1] : sd) : dd[j];
                    ii[j] = m1 ? (m2 ? ii[j - 1] : i) : ii[j];
                }
                if (zp < kk[0]) { kk[0] = zp; dd[0] = sd; ii[0] = i; }
            }
        }
    }

#pragma unroll
    for (int j = 0; j < 8; ++j) {
        s_tz[sl][p][j] = kk[j];
        s_td[sl][p][j] = dd[j];
        s_ti[sl][p][j] = ii[j];
    }
    __syncthreads();

    // ---------------- Phase 4: merge + shade (wave 0) ----------------
    if (tid < 64) {
        int h0 = 0, h1 = 0, h2 = 0, h3 = 0;
        float z0h = s_tz[0][tid][0], z1h = s_tz[1][tid][0];
        float z2h = s_tz[2][tid][0], z3h = s_tz[3][tid][0];
        float mk[8], md[8];
        int mi[8];
#pragma unroll
        for (int j = 0; j < 8; ++j) {
            int s01 = (z1h < z0h) ? 1 : 0;
            float za = fminf(z0h, z1h);
            int s23 = (z3h < z2h) ? 3 : 2;
            float zb = fminf(z2h, z3h);
            int sw = (zb < za) ? s23 : s01;
            float zw = fminf(za, zb);
            mk[j] = zw;
            if (sw == 0)      { md[j] = s_td[0][tid][h0]; mi[j] = s_ti[0][tid][h0]; ++h0; z0h = (h0 < 8) ? s_tz[0][tid][h0] : __builtin_inff(); }
            else if (sw == 1) { md[j] = s_td[1][tid][h1]; mi[j] = s_ti[1][tid][h1]; ++h1; z1h = (h1 < 8) ? s_tz[1][tid][h1] : __builtin_inff(); }
            else if (sw == 2) { md[j] = s_td[2][tid][h2]; mi[j] = s_ti[2][tid][h2]; ++h2; z2h = (h2 < 8) ? s_tz[2][tid][h2] : __builtin_inff(); }
            else              { md[j] = s_td[3][tid][h3]; mi[j] = s_ti[3][tid][h3]; ++h3; z3h = (h3 < 8) ? s_tz[3][tid][h3] : __builtin_inff(); }
        }

        float m_ = 1e-10f, S = 0.0f, aR = 0.0f, aG = 0.0f, aB = 0.0f, aD = 0.0f;
        float om = 1.0f;
#pragma unroll
        for (int j = 0; j < 8; ++j) {
            const int ci = mi[j];
            if (ci >= 0) {
                const float4* Fp = (const float4*)(&s_f[ci * 28]);
                const float4 f0 = Fp[0], f1 = Fp[1], f3 = Fp[3], f4 = Fp[4], f5 = Fp[5], f6 = Fp[6];
                const float ax = f0.x, ay = f0.y, bx = f0.z, by = f0.w, cx = f1.x, cy = f1.y;
                float w0 = (bx - px) * (cy - py) - (by - py) * (cx - px);
                float w1 = (cx - px) * (ay - py) - (cy - py) * (ax - px);
                float w2 = (ax - px) * (by - py) - (ay - py) * (bx - px);
                float b0 = w0 * f3.w, b1 = w1 * f3.w, b2 = w2 * f3.w;
                float n0 = b0 * f4.w, n1 = b1 * f5.x, n2 = b2 * f5.y;
                float den = n0 + n1 + n2;
                den = (fabsf(den) < 1e-10f) ? 1e-10f : den;
                float iden = 1.0f / den;
                float c0 = fmaxf(n0 * iden, 0.0f);
                float c1 = fmaxf(n1 * iden, 0.0f);
                float c2 = fmaxf(n2 * iden, 0.0f);
                float iscn = 1.0f / fmaxf(c0 + c1 + c2, 1e-10f);
                float bc0 = c0 * iscn, bc1 = c1 * iscn, bc2 = c2 * iscn;
                float u = bc0 * f5.z + bc1 * f6.x + bc2 * f6.z;
                float v = bc0 * f5.w + bc1 * f6.y + bc2 * f6.w;
                float tx = u * 127.0f;
                float ty = (1.0f - v) * 127.0f;
                float x0f = fminf(fmaxf(floorf(tx), 0.0f), 127.0f);
                float y0f = fminf(fmaxf(floorf(ty), 0.0f), 127.0f);
                int x0 = (int)x0f, y0 = (int)y0f;
                int x1 = (x0 + 1 < 127) ? x0 + 1 : 127;
                int y1 = (y0 + 1 < 127) ? y0 + 1 : 127;
                float wx = tx - x0f, wy = ty - y0f;
                const float* t00 = texd + (y0 * 128 + x0) * 3;
                const float* t01 = texd + (y0 * 128 + x1) * 3;
                const float* t10 = texd + (y1 * 128 + x0) * 3;
                const float* t11 = texd + (y1 * 128 + x1) * 3;
                float r  = (1.0f - wy) * ((1.0f - wx) * t00[0] + wx * t01[0]) + wy * ((1.0f - wx) * t10[0] + wx * t11[0]);
                float gc = (1.0f - wy) * ((1.0f - wx) * t00[1] + wx * t01[1]) + wy * ((1.0f - wx) * t10[1] + wx * t11[1]);
                float bc = (1.0f - wy) * ((1.0f - wx) * t00[2] + wx * t01[2]) + wy * ((1.0f - wx) * t10[2] + wx * t11[2]);
                float prob = 1.0f / (1.0f + __expf(md[j] * 1e4f));  // sigmoid(-sd/SIGMA)
                float zk = mk[j];
                float zi = (100.0f - zk) * (1.0f / 99.0f);
                om *= (1.0f - prob);
                if (zi > m_) {
                    float scl = __expf((m_ - zi) * 1e4f);
                    S *= scl; aR *= scl; aG *= scl; aB *= scl; aD *= scl;
                    m_ = zi;
                }
                float wgt = prob * __expf((zi - m_) * 1e4f);
                S += wgt; aR += wgt * r; aG += wgt * gc; aB += wgt * bc; aD += wgt * zk;
            }
        }
        float delta = __expf((1e-10f - m_) * 1e4f);
        S += delta;
        aD += delta * 100.0f;  // Z_BACKGROUND
        float invS = 1.0f / S;
        const int o = (y * 128 + x) * 5;
        out[o + 0] = aR * invS;
        out[o + 1] = aG * invS;
        out[o + 2] = aB * invS;
        out[o + 3] = 1.0f - om;
        out[o + 4] = aD * invS;
    }
}

extern "C" void kernel_launch(void* const* d_in, const int* in_sizes, int n_in,
                              void* d_out, int out_size, void* d_ws, size_t ws_size,
                              hipStream_t stream) {
    const float* xy_off = (const float*)d_in[0];
    const float* zg     = (const float*)d_in[1];
    const float* rgb    = (const float*)d_in[2];
    const float* R_in   = (const float*)d_in[3];
    const float* T_in   = (const float*)d_in[4];
    const float* R_out  = (const float*)d_in[5];
    const float* T_out  = (const float*)d_in[6];
    float* out = (float*)d_out;
    nvp_kernel<<<dim3(256), dim3(256), 0, stream>>>(xy_off, zg, rgb, R_in, T_in,
                                                    R_out, T_out, out);
}